// Round 1
// baseline (264.510 us; speedup 1.0000x reference)
//
#include <hip/hip_runtime.h>
#include <hip/hip_bf16.h>
#include <math.h>

typedef _Float16 half8 __attribute__((ext_vector_type(8)));
typedef _Float16 half4v __attribute__((ext_vector_type(4)));
typedef float f32x4 __attribute__((ext_vector_type(4)));

#define NB 8
#define NAA 20
#define ND 16
#define NL 512
#define NC2 4096
#define NC 2048
#define NF 12
#define NR 96      // B*F rows
#define NK 1024    // 2*L contraction for conv GEMM
#define CT 128     // c-tile (conv GEMM N-tile)
#define KC 64      // staged K-chunk (conv GEMM)
#define LSTR 72    // LDS row stride in halves (144B: 16B-aligned, 2-way banks = free)
#define KSPLIT 8
#define CCH 32
#define NTL 256

// ---------- Kernel A: G[d][r][j] = sum_n conv_w[f][n][k] * aa[b][n][d*L+s]
// j = k*512 + s so that G row matches Adj_d = adjs[d] reinterpreted [2048][1024].
__global__ __launch_bounds__(256) void k_g(const float* __restrict__ aa,
                                           const float* __restrict__ conv_w,
                                           _Float16* __restrict__ G) {
  int idx = blockIdx.x * 256 + threadIdx.x;   // 16*96*1024 total
  int j  = idx & (NK - 1);
  int rd = idx >> 10;
  int r  = rd % NR;
  int d  = rd / NR;
  int k  = j >> 9;
  int s  = j & (NL - 1);
  int b  = r / NF;
  int f  = r % NF;
  const float* aap = aa + (size_t)(b * NAA) * (ND * NL) + d * NL + s;
  const float* wp  = conv_w + f * NAA * 2 + k;
  float acc = 0.f;
#pragma unroll
  for (int n = 0; n < NAA; ++n)
    acc += wp[n * 2] * aap[(size_t)n * (ND * NL)];
  G[idx] = (_Float16)acc;
}

// ---------- Kernel B: conv[d][96][2048] = G_d x Adj_d^T  (+ deg column sums)
__global__ __launch_bounds__(256) void k_conv(const float* __restrict__ adjs,
                                              const _Float16* __restrict__ G,
                                              _Float16* __restrict__ conv,
                                              float* __restrict__ deg) {
  __shared__ _Float16 lA[NR][LSTR];
  __shared__ _Float16 lB[CT][LSTR];
  __shared__ float degp[16][16][4];   // [col-group][partial][4 cols]
  int t = threadIdx.x;
  int w = t >> 6;
  int lane = t & 63;
  int ct = blockIdx.x;      // 0..15
  int d  = blockIdx.y;      // 0..15
  int c0 = ct * CT;
  const float*     Adj = adjs + (size_t)d * NC2 * NL;   // as [2048][1024] row-major
  const _Float16*  Gd  = G + (size_t)d * NR * NK;

  f32x4 acc[6][2];
#pragma unroll
  for (int i = 0; i < 6; ++i)
#pragma unroll
    for (int q = 0; q < 2; ++q) acc[i][q] = (f32x4)0.f;

  int brow0 = t >> 4;       // 0..15
  int col4  = t & 15;       // 0..15

  for (int kc = 0; kc < NK / KC; ++kc) {
    // stage A tile: 96 x 64 halves, 16B chunks, 3 per thread
#pragma unroll
    for (int i = 0; i < 3; ++i) {
      int q = i * 256 + t;
      int row = q >> 3;
      int c8  = q & 7;
      uint4 v = *(const uint4*)(Gd + (size_t)row * NK + kc * KC + c8 * 8);
      *(uint4*)(&lA[row][c8 * 8]) = v;
    }
    // stage B tile (fp32 -> fp16) + per-thread column partial sums for deg
    float cs0 = 0, cs1 = 0, cs2 = 0, cs3 = 0;
#pragma unroll
    for (int i = 0; i < 8; ++i) {
      int row = brow0 + i * 16;
      const float4 v = *(const float4*)(Adj + (size_t)(c0 + row) * NK + kc * KC + col4 * 4);
      cs0 += v.x; cs1 += v.y; cs2 += v.z; cs3 += v.w;
      half4v hv = {(_Float16)v.x, (_Float16)v.y, (_Float16)v.z, (_Float16)v.w};
      *(half4v*)(&lB[row][col4 * 4]) = hv;
    }
    degp[col4][brow0][0] = cs0;
    degp[col4][brow0][1] = cs1;
    degp[col4][brow0][2] = cs2;
    degp[col4][brow0][3] = cs3;
    __syncthreads();
    // deg reduction: 64 columns this chunk
    if (t < 64) {
      int cg = t >> 2, ci = t & 3;
      float sum = 0.f;
#pragma unroll
      for (int p = 0; p < 16; ++p) sum += degp[cg][p][ci];
      int j = kc * KC + cg * 4 + ci;
      int s = j & (NL - 1);
      atomicAdd(deg + d * NL + s, sum);
    }
    // MFMA: 2 k-substeps of 32
#pragma unroll
    for (int ks = 0; ks < 2; ++ks) {
      int ko = ks * 32 + 8 * (lane >> 4);
      half8 b0 = *(const half8*)(&lB[w * 32 + (lane & 15)][ko]);
      half8 b1 = *(const half8*)(&lB[w * 32 + 16 + (lane & 15)][ko]);
#pragma unroll
      for (int mf = 0; mf < 6; ++mf) {
        half8 a = *(const half8*)(&lA[mf * 16 + (lane & 15)][ko]);
        acc[mf][0] = __builtin_amdgcn_mfma_f32_16x16x32_f16(a, b0, acc[mf][0], 0, 0, 0);
        acc[mf][1] = __builtin_amdgcn_mfma_f32_16x16x32_f16(a, b1, acc[mf][1], 0, 0, 0);
      }
    }
    __syncthreads();
  }
  // epilogue: write conv fp16 (K-major for next GEMM's A operand)
  int nbase = c0 + w * 32;
#pragma unroll
  for (int mf = 0; mf < 6; ++mf)
#pragma unroll
    for (int nf = 0; nf < 2; ++nf)
#pragma unroll
      for (int jj = 0; jj < 4; ++jj) {
        int m = mf * 16 + (lane >> 4) * 4 + jj;
        int c = nbase + nf * 16 + (lane & 15);
        conv[((size_t)d * NR + m) * NC + c] = (_Float16)acc[mf][nf][jj];
      }
}

// ---------- Kernel C: aa2[d][96][512] += conv_d x A0_d   (A0 = even adjs rows)
__global__ __launch_bounds__(256) void k_contract(const float* __restrict__ adjs,
                                                  const _Float16* __restrict__ conv,
                                                  float* __restrict__ aa2) {
  __shared__ _Float16 lB[NTL][LSTR];    // [l][c_local], transpose-staged
  int t = threadIdx.x;
  int w = t >> 6;
  int lane = t & 63;
  int nt = blockIdx.x;      // 0..1
  int ks = blockIdx.y;      // 0..7
  int d  = blockIdx.z;      // 0..15
  int l0 = nt * NTL;
  int cbase = ks * (NC / KSPLIT);
  const float* A0 = adjs + (size_t)d * NC2 * NL;

  f32x4 acc[6][4];
#pragma unroll
  for (int i = 0; i < 6; ++i)
#pragma unroll
    for (int q = 0; q < 4; ++q) acc[i][q] = (f32x4)0.f;

  int cl  = t >> 3;          // 0..31 local c
  int lc0 = (t & 7) * 4;

  for (int cc = 0; cc < (NC / KSPLIT) / CCH; ++cc) {   // 8 chunks of 32 c
    int cg = cbase + cc * CCH + cl;                    // global c of this thread's row
#pragma unroll
    for (int i = 0; i < 8; ++i) {
      int lcol = lc0 + i * 32;
      const float4 v = *(const float4*)(A0 + (size_t)(2 * cg) * NL + l0 + lcol);
      lB[lcol + 0][cl] = (_Float16)v.x;
      lB[lcol + 1][cl] = (_Float16)v.y;
      lB[lcol + 2][cl] = (_Float16)v.z;
      lB[lcol + 3][cl] = (_Float16)v.w;
    }
    __syncthreads();
    int kofs = cbase + cc * CCH + 8 * (lane >> 4);
    half8 bfr[4];
#pragma unroll
    for (int nf = 0; nf < 4; ++nf)
      bfr[nf] = *(const half8*)(&lB[w * 64 + nf * 16 + (lane & 15)][8 * (lane >> 4)]);
#pragma unroll
    for (int mf = 0; mf < 6; ++mf) {
      half8 a = *(const half8*)(conv + ((size_t)d * NR + mf * 16 + (lane & 15)) * NC + kofs);
#pragma unroll
      for (int nf = 0; nf < 4; ++nf)
        acc[mf][nf] = __builtin_amdgcn_mfma_f32_16x16x32_f16(a, bfr[nf], acc[mf][nf], 0, 0, 0);
    }
    __syncthreads();
  }
#pragma unroll
  for (int mf = 0; mf < 6; ++mf)
#pragma unroll
    for (int nf = 0; nf < 4; ++nf)
#pragma unroll
      for (int jj = 0; jj < 4; ++jj) {
        int m = mf * 16 + (lane >> 4) * 4 + jj;
        int l = l0 + w * 64 + nf * 16 + (lane & 15);
        atomicAdd(aa2 + ((size_t)d * NR + m) * NL + l, acc[mf][nf][jj]);
      }
}

// ---------- Kernel D: dmax -> linear -> sigmoid
__global__ __launch_bounds__(64) void k_final(const float* __restrict__ aa2,
                                              const float* __restrict__ deg,
                                              const float* __restrict__ lin_w,
                                              float* __restrict__ out) {
  int t = threadIdx.x;        // 0..63
  int bidx = blockIdx.x;      // d*8 + b
  int d = bidx >> 3;
  int b = bidx & 7;
  float inv[8];
#pragma unroll
  for (int i = 0; i < 8; ++i)
    inv[i] = 1.0f / deg[d * NL + t + i * 64];
  float score = 0.f;
  for (int f = 0; f < NF; ++f) {
    const float* row = aa2 + ((size_t)d * NR + b * NF + f) * NL;
    float m = -1e30f;
#pragma unroll
    for (int i = 0; i < 8; ++i) {
      float v = row[t + i * 64] * inv[i];
      m = fmaxf(m, v);
    }
#pragma unroll
    for (int off = 32; off >= 1; off >>= 1)
      m = fmaxf(m, __shfl_xor(m, off));
    score += m * lin_w[f];
  }
  if (t == 0) out[(size_t)d * NB + b] = 1.f / (1.f + expf(-score));
}

extern "C" void kernel_launch(void* const* d_in, const int* in_sizes, int n_in,
                              void* d_out, int out_size, void* d_ws, size_t ws_size,
                              hipStream_t stream) {
  const float* aa     = (const float*)d_in[0];
  const float* adjs   = (const float*)d_in[1];
  const float* conv_w = (const float*)d_in[2];
  const float* lin_w  = (const float*)d_in[3];
  float* out = (float*)d_out;

  char* ws = (char*)d_ws;
  _Float16* G    = (_Float16*)ws;                         // 3,145,728 B
  _Float16* conv = (_Float16*)(ws + 3145728);             // 6,291,456 B
  float*    aa2  = (float*)(ws + 3145728 + 6291456);      // 3,145,728 B
  float*    deg  = (float*)(ws + 3145728 + 6291456 + 3145728); // 32 KB

  // zero the accumulators (aa2 + deg are contiguous)
  hipMemsetAsync(aa2, 0, 3145728 + ND * NL * sizeof(float), stream);

  k_g<<<dim3((ND * NR * NK) / 256), 256, 0, stream>>>(aa, conv_w, G);
  k_conv<<<dim3(NC / CT, ND), 256, 0, stream>>>(adjs, G, conv, deg);
  k_contract<<<dim3(NL / NTL, KSPLIT, ND), 256, 0, stream>>>(adjs, conv, aa2);
  k_final<<<dim3(ND * NB), 64, 0, stream>>>(aa2, deg, lin_w, out);
}

// Round 2
// 252.820 us; speedup vs baseline: 1.0462x; 1.0462x over previous
//
#include <hip/hip_runtime.h>
#include <hip/hip_bf16.h>
#include <math.h>

typedef _Float16 half8 __attribute__((ext_vector_type(8)));
typedef _Float16 half4v __attribute__((ext_vector_type(4)));
typedef float f32x4 __attribute__((ext_vector_type(4)));

#define NB 8
#define NAA 20
#define ND 16
#define NL 512
#define NC2 4096
#define NC 2048
#define NF 12
#define NR 96      // B*F rows
#define NK 1024    // 2*L contraction for conv GEMM
#define CT 128     // c-tile (conv GEMM N-tile)
#define KC 64      // staged K-chunk (conv GEMM)
#define LSTR 72    // LDS row stride in halves

// ---------- Kernel A: G[d][r][j] = sum_n conv_w[f][n][k] * aa[b][n][d*L+s]
// j = k*512 + s so that G row matches Adj_d = adjs[d] reinterpreted [2048][1024].
__global__ __launch_bounds__(256) void k_g(const float* __restrict__ aa,
                                           const float* __restrict__ conv_w,
                                           _Float16* __restrict__ G) {
  int idx = blockIdx.x * 256 + threadIdx.x;   // 16*96*1024 total
  int j  = idx & (NK - 1);
  int rd = idx >> 10;
  int r  = rd % NR;
  int d  = rd / NR;
  int k  = j >> 9;
  int s  = j & (NL - 1);
  int b  = r / NF;
  int f  = r % NF;
  const float* aap = aa + (size_t)(b * NAA) * (ND * NL) + d * NL + s;
  const float* wp  = conv_w + f * NAA * 2 + k;
  float acc = 0.f;
#pragma unroll
  for (int n = 0; n < NAA; ++n)
    acc += wp[n * 2] * aap[(size_t)n * (ND * NL)];
  G[idx] = (_Float16)acc;
}

// ---------- Kernel B: conv[d][96][2048] = G_d x Adj_d^T  (+ deg column sums)
__global__ __launch_bounds__(256) void k_conv(const float* __restrict__ adjs,
                                              const _Float16* __restrict__ G,
                                              _Float16* __restrict__ conv,
                                              float* __restrict__ deg) {
  __shared__ _Float16 lA[NR][LSTR];
  __shared__ _Float16 lB[CT][LSTR];
  __shared__ float degp[16][16][4];   // [col-group][partial][4 cols]
  int t = threadIdx.x;
  int w = t >> 6;
  int lane = t & 63;
  int ct = blockIdx.x;      // 0..15
  int d  = blockIdx.y;      // 0..15
  int c0 = ct * CT;
  const float*     Adj = adjs + (size_t)d * NC2 * NL;   // as [2048][1024] row-major
  const _Float16*  Gd  = G + (size_t)d * NR * NK;

  f32x4 acc[6][2];
#pragma unroll
  for (int i = 0; i < 6; ++i)
#pragma unroll
    for (int q = 0; q < 2; ++q) acc[i][q] = (f32x4)0.f;

  int brow0 = t >> 4;       // 0..15
  int col4  = t & 15;       // 0..15

  for (int kc = 0; kc < NK / KC; ++kc) {
    // stage A tile: 96 x 64 halves, 16B chunks, 3 per thread
#pragma unroll
    for (int i = 0; i < 3; ++i) {
      int q = i * 256 + t;
      int row = q >> 3;
      int c8  = q & 7;
      uint4 v = *(const uint4*)(Gd + (size_t)row * NK + kc * KC + c8 * 8);
      *(uint4*)(&lA[row][c8 * 8]) = v;
    }
    // stage B tile (fp32 -> fp16) + per-thread column partial sums for deg
    float cs0 = 0, cs1 = 0, cs2 = 0, cs3 = 0;
#pragma unroll
    for (int i = 0; i < 8; ++i) {
      int row = brow0 + i * 16;
      const float4 v = *(const float4*)(Adj + (size_t)(c0 + row) * NK + kc * KC + col4 * 4);
      cs0 += v.x; cs1 += v.y; cs2 += v.z; cs3 += v.w;
      half4v hv = {(_Float16)v.x, (_Float16)v.y, (_Float16)v.z, (_Float16)v.w};
      *(half4v*)(&lB[row][col4 * 4]) = hv;
    }
    degp[col4][brow0][0] = cs0;
    degp[col4][brow0][1] = cs1;
    degp[col4][brow0][2] = cs2;
    degp[col4][brow0][3] = cs3;
    __syncthreads();
    // deg reduction: 64 columns this chunk
    if (t < 64) {
      int cg = t >> 2, ci = t & 3;
      float sum = 0.f;
#pragma unroll
      for (int p = 0; p < 16; ++p) sum += degp[cg][p][ci];
      int j = kc * KC + cg * 4 + ci;
      int s = j & (NL - 1);
      atomicAdd(deg + d * NL + s, sum);
    }
    // MFMA: 2 k-substeps of 32
#pragma unroll
    for (int ks = 0; ks < 2; ++ks) {
      int ko = ks * 32 + 8 * (lane >> 4);
      half8 b0 = *(const half8*)(&lB[w * 32 + (lane & 15)][ko]);
      half8 b1 = *(const half8*)(&lB[w * 32 + 16 + (lane & 15)][ko]);
#pragma unroll
      for (int mf = 0; mf < 6; ++mf) {
        half8 a = *(const half8*)(&lA[mf * 16 + (lane & 15)][ko]);
        acc[mf][0] = __builtin_amdgcn_mfma_f32_16x16x32_f16(a, b0, acc[mf][0], 0, 0, 0);
        acc[mf][1] = __builtin_amdgcn_mfma_f32_16x16x32_f16(a, b1, acc[mf][1], 0, 0, 0);
      }
    }
    __syncthreads();
  }
  // epilogue: write conv fp16 (K-major for next GEMM's A operand)
  int nbase = c0 + w * 32;
#pragma unroll
  for (int mf = 0; mf < 6; ++mf)
#pragma unroll
    for (int nf = 0; nf < 2; ++nf)
#pragma unroll
      for (int jj = 0; jj < 4; ++jj) {
        int m = mf * 16 + (lane >> 4) * 4 + jj;
        int c = nbase + nf * 16 + (lane & 15);
        conv[((size_t)d * NR + m) * NC + c] = (_Float16)acc[mf][nf][jj];
      }
}

// ---------- Kernel C v2: aa2p[ks][d][96][512] = partial conv_d x A0_d
// LDS-free: B-fragments built directly from global (coalesced 64B per 16-lane
// group), A-fragments straight from conv (fp16, 64B-coalesced). No atomics:
// KSPLIT=2 partials written to disjoint buffers, combined in k_final.
__global__ __launch_bounds__(256) void k_contract(const float* __restrict__ adjs,
                                                  const _Float16* __restrict__ conv,
                                                  float* __restrict__ aa2p) {
  int bid  = blockIdx.x;          // 256 blocks
  int xcd  = bid & 7;
  int slot = bid >> 3;            // 0..31
  int d    = xcd * 2 + (slot & 1);   // all blocks of a domain share an XCD
  int r2   = slot >> 1;           // 0..15
  int ks   = r2 & 1;              // K-half
  int lt   = r2 >> 1;             // 0..7 l-tile of 64
  int t    = threadIdx.x;
  int w    = t >> 6;
  int lane = t & 63;
  int l16  = lane & 15;
  int kg   = lane >> 4;           // 0..3
  int gl_l = lt * 64 + w * 16 + l16;
  const float*    A0    = adjs + (size_t)d * NC2 * NL;  // even rows used
  const _Float16* convd = conv + (size_t)d * NR * NC;

  f32x4 acc[6];
#pragma unroll
  for (int i = 0; i < 6; ++i) acc[i] = (f32x4)0.f;

#pragma unroll 2
  for (int cc = 0; cc < 32; ++cc) {       // K = 1024 in steps of 32
    int cb = ks * 1024 + cc * 32 + kg * 8;   // this lane-group's 8 c-rows
    float bv[8];
#pragma unroll
    for (int j = 0; j < 8; ++j)
      bv[j] = A0[(size_t)(2 * (cb + j)) * NL + gl_l];
    half8 b;
#pragma unroll
    for (int j = 0; j < 8; ++j) b[j] = (_Float16)bv[j];
#pragma unroll
    for (int mf = 0; mf < 6; ++mf) {
      half8 a = *(const half8*)(convd + (size_t)(mf * 16 + l16) * NC + cb);
      acc[mf] = __builtin_amdgcn_mfma_f32_16x16x32_f16(a, b, acc[mf], 0, 0, 0);
    }
  }
  float* outp = aa2p + (size_t)(ks * ND + d) * NR * NL;
#pragma unroll
  for (int mf = 0; mf < 6; ++mf)
#pragma unroll
    for (int jj = 0; jj < 4; ++jj) {
      int m = mf * 16 + kg * 4 + jj;
      outp[(size_t)m * NL + gl_l] = acc[mf][jj];
    }
}

// ---------- Kernel D: combine partials -> /deg -> max_l -> dot(lin_w) -> sigmoid
__global__ __launch_bounds__(256) void k_final(const float* __restrict__ aa2p,
                                               const float* __restrict__ deg,
                                               const float* __restrict__ lin_w,
                                               float* __restrict__ out) {
  __shared__ float partw[4];
  int t = threadIdx.x;
  int w = t >> 6, lane = t & 63;
  int d = blockIdx.x >> 3, b = blockIdx.x & 7;
  float inv[8];
#pragma unroll
  for (int i = 0; i < 8; ++i)
    inv[i] = 1.0f / deg[d * NL + lane + i * 64];
  float part = 0.f;
#pragma unroll
  for (int q = 0; q < 3; ++q) {
    int f = w * 3 + q;                       // 4 waves x 3 filters = 12
    const float* p0 = aa2p + ((size_t)d * NR + b * NF + f) * NL;
    const float* p1 = p0 + (size_t)ND * NR * NL;
    float m = -1e30f;
#pragma unroll
    for (int i = 0; i < 8; ++i) {
      int l = lane + i * 64;
      m = fmaxf(m, (p0[l] + p1[l]) * inv[i]);
    }
#pragma unroll
    for (int off = 32; off >= 1; off >>= 1)
      m = fmaxf(m, __shfl_xor(m, off));
    part += m * lin_w[f];
  }
  if (lane == 0) partw[w] = part;
  __syncthreads();
  if (t == 0) {
    float s = partw[0] + partw[1] + partw[2] + partw[3];
    out[d * NB + b] = 1.f / (1.f + expf(-s));
  }
}

extern "C" void kernel_launch(void* const* d_in, const int* in_sizes, int n_in,
                              void* d_out, int out_size, void* d_ws, size_t ws_size,
                              hipStream_t stream) {
  const float* aa     = (const float*)d_in[0];
  const float* adjs   = (const float*)d_in[1];
  const float* conv_w = (const float*)d_in[2];
  const float* lin_w  = (const float*)d_in[3];
  float* out = (float*)d_out;

  char* ws = (char*)d_ws;
  _Float16* G    = (_Float16*)ws;                          // 3,145,728 B
  _Float16* conv = (_Float16*)(ws + 3145728);              // 6,291,456 B
  float*    aa2p = (float*)(ws + 3145728 + 6291456);       // 6,291,456 B (2 partials)
  float*    deg  = (float*)(ws + 3145728 + 6291456 + 6291456); // 32 KB

  hipMemsetAsync(deg, 0, ND * NL * sizeof(float), stream);

  k_g<<<dim3((ND * NR * NK) / 256), 256, 0, stream>>>(aa, conv_w, G);
  k_conv<<<dim3(NC / CT, ND), 256, 0, stream>>>(adjs, G, conv, deg);
  k_contract<<<dim3(256), 256, 0, stream>>>(adjs, conv, aa2p);
  k_final<<<dim3(ND * NB), 256, 0, stream>>>(aa2p, deg, lin_w, out);
}

// Round 3
// 249.038 us; speedup vs baseline: 1.0621x; 1.0152x over previous
//
#include <hip/hip_runtime.h>
#include <hip/hip_bf16.h>
#include <math.h>

typedef _Float16 half8 __attribute__((ext_vector_type(8)));
typedef _Float16 half4v __attribute__((ext_vector_type(4)));
typedef float f32x4 __attribute__((ext_vector_type(4)));

#define NB 8
#define NAA 20
#define ND 16
#define NL 512
#define NC2 4096
#define NC 2048
#define NF 12
#define NR 96      // B*F rows
#define NK 1024    // 2*L contraction for conv GEMM
#define CT 128     // c-tile (conv GEMM N-tile)
#define KC 64      // staged K-chunk (conv GEMM)
#define LSTR 72    // LDS row stride in halves
#define KSP 8      // contract split-K
#define BSTR 260   // contract B LDS stride (halves): conflict-free frag gather

// ---------- Kernel A: G[d][r][j] = sum_n conv_w[f][n][k] * aa[b][n][d*L+s]
// j = k*512 + s so that G row matches Adj_d = adjs[d] reinterpreted [2048][1024].
__global__ __launch_bounds__(256) void k_g(const float* __restrict__ aa,
                                           const float* __restrict__ conv_w,
                                           _Float16* __restrict__ G) {
  int idx = blockIdx.x * 256 + threadIdx.x;   // 16*96*1024 total
  int j  = idx & (NK - 1);
  int rd = idx >> 10;
  int r  = rd % NR;
  int d  = rd / NR;
  int k  = j >> 9;
  int s  = j & (NL - 1);
  int b  = r / NF;
  int f  = r % NF;
  const float* aap = aa + (size_t)(b * NAA) * (ND * NL) + d * NL + s;
  const float* wp  = conv_w + f * NAA * 2 + k;
  float acc = 0.f;
#pragma unroll
  for (int n = 0; n < NAA; ++n)
    acc += wp[n * 2] * aap[(size_t)n * (ND * NL)];
  G[idx] = (_Float16)acc;
}

// ---------- Kernel B: conv[d][96][2048] = G_d x Adj_d^T  (+ deg column sums)
__global__ __launch_bounds__(256) void k_conv(const float* __restrict__ adjs,
                                              const _Float16* __restrict__ G,
                                              _Float16* __restrict__ conv,
                                              float* __restrict__ deg) {
  __shared__ _Float16 lA[NR][LSTR];
  __shared__ _Float16 lB[CT][LSTR];
  __shared__ float degp[16][16][4];   // [col-group][partial][4 cols]
  int t = threadIdx.x;
  int w = t >> 6;
  int lane = t & 63;
  int ct = blockIdx.x;      // 0..15
  int d  = blockIdx.y;      // 0..15
  int c0 = ct * CT;
  const float*     Adj = adjs + (size_t)d * NC2 * NL;   // as [2048][1024] row-major
  const _Float16*  Gd  = G + (size_t)d * NR * NK;

  f32x4 acc[6][2];
#pragma unroll
  for (int i = 0; i < 6; ++i)
#pragma unroll
    for (int q = 0; q < 2; ++q) acc[i][q] = (f32x4)0.f;

  int brow0 = t >> 4;       // 0..15
  int col4  = t & 15;       // 0..15

  for (int kc = 0; kc < NK / KC; ++kc) {
    // stage A tile: 96 x 64 halves, 16B chunks, 3 per thread
#pragma unroll
    for (int i = 0; i < 3; ++i) {
      int q = i * 256 + t;
      int row = q >> 3;
      int c8  = q & 7;
      uint4 v = *(const uint4*)(Gd + (size_t)row * NK + kc * KC + c8 * 8);
      *(uint4*)(&lA[row][c8 * 8]) = v;
    }
    // stage B tile (fp32 -> fp16) + per-thread column partial sums for deg
    float cs0 = 0, cs1 = 0, cs2 = 0, cs3 = 0;
#pragma unroll
    for (int i = 0; i < 8; ++i) {
      int row = brow0 + i * 16;
      const float4 v = *(const float4*)(Adj + (size_t)(c0 + row) * NK + kc * KC + col4 * 4);
      cs0 += v.x; cs1 += v.y; cs2 += v.z; cs3 += v.w;
      half4v hv = {(_Float16)v.x, (_Float16)v.y, (_Float16)v.z, (_Float16)v.w};
      *(half4v*)(&lB[row][col4 * 4]) = hv;
    }
    degp[col4][brow0][0] = cs0;
    degp[col4][brow0][1] = cs1;
    degp[col4][brow0][2] = cs2;
    degp[col4][brow0][3] = cs3;
    __syncthreads();
    // deg reduction: 64 columns this chunk
    if (t < 64) {
      int cg = t >> 2, ci = t & 3;
      float sum = 0.f;
#pragma unroll
      for (int p = 0; p < 16; ++p) sum += degp[cg][p][ci];
      int j = kc * KC + cg * 4 + ci;
      int s = j & (NL - 1);
      atomicAdd(deg + d * NL + s, sum);
    }
    // MFMA: 2 k-substeps of 32
#pragma unroll
    for (int ks = 0; ks < 2; ++ks) {
      int ko = ks * 32 + 8 * (lane >> 4);
      half8 b0 = *(const half8*)(&lB[w * 32 + (lane & 15)][ko]);
      half8 b1 = *(const half8*)(&lB[w * 32 + 16 + (lane & 15)][ko]);
#pragma unroll
      for (int mf = 0; mf < 6; ++mf) {
        half8 a = *(const half8*)(&lA[mf * 16 + (lane & 15)][ko]);
        acc[mf][0] = __builtin_amdgcn_mfma_f32_16x16x32_f16(a, b0, acc[mf][0], 0, 0, 0);
        acc[mf][1] = __builtin_amdgcn_mfma_f32_16x16x32_f16(a, b1, acc[mf][1], 0, 0, 0);
      }
    }
    __syncthreads();
  }
  // epilogue: write conv fp16 (K-major for next GEMM's A operand)
  int nbase = c0 + w * 32;
#pragma unroll
  for (int mf = 0; mf < 6; ++mf)
#pragma unroll
    for (int nf = 0; nf < 2; ++nf)
#pragma unroll
      for (int jj = 0; jj < 4; ++jj) {
        int m = mf * 16 + (lane >> 4) * 4 + jj;
        int c = nbase + nf * 16 + (lane & 15);
        conv[((size_t)d * NR + m) * NC + c] = (_Float16)acc[mf][nf][jj];
      }
}

// ---------- Kernel C v3: proper LDS-tiled GEMM.
// Block (d, ks in 0..7, lh in 0..1): aa2p[ks][d][96][lh*256..+256] =
//   conv[d][96][ks*256..+256] x A0[d][ks*256..+256][lh*256..+256]
// B staged [64c][256l] fp16 stride 260h (frag gather conflict-free);
// A staged [96][64] with 16B-unit XOR swizzle. No atomics.
__global__ __launch_bounds__(256) void k_contract(const float* __restrict__ adjs,
                                                  const _Float16* __restrict__ conv,
                                                  float* __restrict__ aa2p) {
  __shared__ _Float16 lB[64 * BSTR];
  __shared__ _Float16 lA[96 * LSTR];
  int bid = blockIdx.x;
  int xcd = bid & 7, grp = bid >> 3;
  int d = xcd * 2 + (grp & 1);
  int rest = grp >> 1;        // 0..15
  int ks = rest & 7;
  int lh = rest >> 3;
  int t = threadIdx.x, w = t >> 6, lane = t & 63;
  int l16 = lane & 15, kg = lane >> 4;
  int cbase = ks * 256;
  int l0g = lh * 256;
  const float*    A0    = adjs + (size_t)d * NC2 * NL;
  const _Float16* convd = conv + (size_t)d * NR * NC;

  f32x4 acc[6][4];
#pragma unroll
  for (int i = 0; i < 6; ++i)
#pragma unroll
    for (int q = 0; q < 4; ++q) acc[i][q] = (f32x4)0.f;

  for (int cc = 0; cc < 4; ++cc) {        // 4 chunks of 64 c
    // stage B: 64 c-rows x 256 l, fp32->fp16, fully coalesced (1KB rows)
#pragma unroll
    for (int i = 0; i < 16; ++i) {
      int unit = i * 256 + t;
      int c_l = unit >> 6;
      int lu  = unit & 63;
      const float4 v = *(const float4*)(A0 + (size_t)(2 * (cbase + cc * 64 + c_l)) * NL + l0g + lu * 4);
      half4v hv = {(_Float16)v.x, (_Float16)v.y, (_Float16)v.z, (_Float16)v.w};
      *(half4v*)(&lB[c_l * BSTR + lu * 4]) = hv;
    }
    // stage A: 96 m-rows x 64 c halves, 16B units XOR-swizzled
#pragma unroll
    for (int i = 0; i < 3; ++i) {
      int idx = i * 256 + t;
      int row = idx >> 3, u = idx & 7;
      half8 v = *(const half8*)(convd + (size_t)row * NC + cbase + cc * 64 + u * 8);
      *(half8*)(&lA[row * LSTR + ((u ^ (row & 7)) * 8)]) = v;
    }
    __syncthreads();
#pragma unroll
    for (int ks2 = 0; ks2 < 2; ++ks2) {
      half8 bfr[4];
#pragma unroll
      for (int nf = 0; nf < 4; ++nf) {
        int lcol = w * 64 + nf * 16 + l16;
#pragma unroll
        for (int j = 0; j < 8; ++j)
          bfr[nf][j] = lB[(ks2 * 32 + kg * 8 + j) * BSTR + lcol];
      }
#pragma unroll
      for (int mf = 0; mf < 6; ++mf) {
        int m = mf * 16 + l16;
        half8 a = *(const half8*)(&lA[m * LSTR + (((ks2 * 4 + kg) ^ (l16 & 7)) * 8)]);
#pragma unroll
        for (int nf = 0; nf < 4; ++nf)
          acc[mf][nf] = __builtin_amdgcn_mfma_f32_16x16x32_f16(a, bfr[nf], acc[mf][nf], 0, 0, 0);
      }
    }
    __syncthreads();
  }
  float* outp = aa2p + (size_t)(ks * ND + d) * NR * NL;
#pragma unroll
  for (int mf = 0; mf < 6; ++mf)
#pragma unroll
    for (int nf = 0; nf < 4; ++nf)
#pragma unroll
      for (int jj = 0; jj < 4; ++jj) {
        int m = mf * 16 + kg * 4 + jj;
        int l = l0g + w * 64 + nf * 16 + l16;
        outp[(size_t)m * NL + l] = acc[mf][nf][jj];
      }
}

// ---------- Kernel D: sum 8 partials -> /deg -> max_l -> dot(lin_w) -> sigmoid
__global__ __launch_bounds__(256) void k_final(const float* __restrict__ aa2p,
                                               const float* __restrict__ deg,
                                               const float* __restrict__ lin_w,
                                               float* __restrict__ out) {
  __shared__ float partw[4];
  int t = threadIdx.x;
  int w = t >> 6, lane = t & 63;
  int d = blockIdx.x >> 3, b = blockIdx.x & 7;
  float inv[8];
#pragma unroll
  for (int i = 0; i < 8; ++i)
    inv[i] = 1.0f / deg[d * NL + lane + i * 64];
  float part = 0.f;
#pragma unroll
  for (int q = 0; q < 3; ++q) {
    int f = w * 3 + q;                       // 4 waves x 3 filters = 12
    float m = -1e30f;
#pragma unroll
    for (int i = 0; i < 8; ++i) {
      int l = lane + i * 64;
      float s = 0.f;
#pragma unroll
      for (int ks = 0; ks < KSP; ++ks)
        s += aa2p[((size_t)(ks * ND + d) * NR + b * NF + f) * NL + l];
      m = fmaxf(m, s * inv[i]);
    }
#pragma unroll
    for (int off = 32; off >= 1; off >>= 1)
      m = fmaxf(m, __shfl_xor(m, off));
    part += m * lin_w[f];
  }
  if (lane == 0) partw[w] = part;
  __syncthreads();
  if (t == 0) {
    float s = partw[0] + partw[1] + partw[2] + partw[3];
    out[d * NB + b] = 1.f / (1.f + expf(-s));
  }
}

extern "C" void kernel_launch(void* const* d_in, const int* in_sizes, int n_in,
                              void* d_out, int out_size, void* d_ws, size_t ws_size,
                              hipStream_t stream) {
  const float* aa     = (const float*)d_in[0];
  const float* adjs   = (const float*)d_in[1];
  const float* conv_w = (const float*)d_in[2];
  const float* lin_w  = (const float*)d_in[3];
  float* out = (float*)d_out;

  char* ws = (char*)d_ws;
  _Float16* G    = (_Float16*)ws;                          // 3,145,728 B
  _Float16* conv = (_Float16*)(ws + 3145728);              // 6,291,456 B
  float*    aa2p = (float*)(ws + 9437184);                 // 8 partials: 25,165,824 B
  float*    deg  = (float*)(ws + 9437184 + 25165824);      // 32 KB

  hipMemsetAsync(deg, 0, ND * NL * sizeof(float), stream);

  k_g<<<dim3((ND * NR * NK) / 256), 256, 0, stream>>>(aa, conv_w, G);
  k_conv<<<dim3(NC / CT, ND), 256, 0, stream>>>(adjs, G, conv, deg);
  k_contract<<<dim3(256), 256, 0, stream>>>(adjs, conv, aa2p);
  k_final<<<dim3(ND * NB), 256, 0, stream>>>(aa2p, deg, lin_w, out);
}